// Round 8
// baseline (1944.397 us; speedup 1.0000x reference)
//
#include <hip/hip_runtime.h>
#include <stdint.h>

#define B_ 8
#define D_ 128
#define T_ 4096
#define Q_ 30
#define C_ 1024

typedef __attribute__((ext_vector_type(8))) _Float16 half8;
typedef __attribute__((ext_vector_type(4))) float float4_;

// fp16 codebook chunk images: 240 chunks (q*8+c) of 128 codes x 128 dims,
// XOR-swizzled 16B granules, byte-identical to the LDS image -> raw DMA staging.
__device__ __align__(16) _Float16 g_half[(size_t)Q_*8*16384];

typedef __attribute__((address_space(3))) void lds_void;
typedef __attribute__((address_space(1))) const void gbl_void;
__device__ __forceinline__ void gld16(const void* g, void* l){
  __builtin_amdgcn_global_load_lds((gbl_void*)g, (lds_void*)l, 16, 0, 0);
}

// ---------------- prep 1: per-code ||c||^2, fp64 accumulation ----------------
__global__ void rvq_prep(const float* __restrict__ cb, float* __restrict__ sumsq){
  int g    = blockIdx.x*128 + (threadIdx.x>>1);
  int half = threadIdx.x & 1;
  const float* src = cb + (size_t)g*D_ + half*64;
  double s = 0.0;
#pragma unroll
  for (int i=0;i<64;i+=4){
    float4_ f = *(const float4_*)(src+i);
    s += (double)f.x*f.x + (double)f.y*f.y + (double)f.z*f.z + (double)f.w*f.w;
  }
  s += __shfl_xor(s, 1);
  if (!half) sumsq[g] = (float)s;
}

// ---------------- prep 2: build swizzled fp16 chunk images -------------------
__global__ void rvq_split(const float* __restrict__ cb){
  const int bI   = blockIdx.x;            // chunk id 0..239 (q*8+c)
  const int tid  = threadIdx.x;
  const int crel = tid>>1, part = tid&1;  // code-in-chunk, dim half
  const int swz  = crel & 15;
  const float* src = cb + ((size_t)bI*128 + crel)*128 + part*64;
  _Float16* dst = g_half + ((size_t)bI<<14) + (crel<<7);
#pragma unroll
  for (int i=0;i<8;++i){
    float4_ f0 = *(const float4_*)(src + i*8);
    float4_ f1 = *(const float4_*)(src + i*8 + 4);
    half8 h;
    h[0]=(_Float16)f0.x; h[1]=(_Float16)f0.y; h[2]=(_Float16)f0.z; h[3]=(_Float16)f0.w;
    h[4]=(_Float16)f1.x; h[5]=(_Float16)f1.y; h[6]=(_Float16)f1.z; h[7]=(_Float16)f1.w;
    const int kg  = part*8 + i;
    const int kgs = kg ^ swz;
    *(half8*)&dst[kgs<<3] = h;
  }
}

// --- main: 30-step RVQ, fp16 scoring + top-4 fp64 rescore, 128-code chunks ---
__global__ __launch_bounds__(256,1) void rvq_main(
    const float* __restrict__ x, const float* __restrict__ cb,
    const float* __restrict__ sumsq, double* __restrict__ lossAcc,
    float* __restrict__ out)
{
  __shared__ _Float16 sBh[2*16384];   // 64KB dbuf, one 32KB fp16 chunk per slot
  __shared__ float sCS[4][32][16][2]; // per-wave per-row per-lane top2 scores
  __shared__ int   sCI[4][32][16][2]; // matching global code ids
  __shared__ int   sI4[4][32][4];     // merged top-4 ids per row
  __shared__ float sCcQ[1024];        // ||c||^2 for current q

  const int tid  = threadIdx.x;
  const int wv   = tid>>6;
  const int ln   = tid&63;
  const int col  = ln&15;
  const int quad = ln>>4;
  const int blk  = blockIdx.x;
  const int b    = blk>>5;
  const int t0   = ((blk&31)<<7) + (wv<<5);

  // residual fp64, A-frag distribution: row = rt*16+col, dim = kc*32+quad*8+j
  double rmast[2][4][8];
#pragma unroll
  for (int rt=0;rt<2;++rt){
    const int t = t0 + rt*16 + col;
#pragma unroll
    for (int kc=0;kc<4;++kc)
#pragma unroll
      for (int j=0;j<8;++j){
        const int d = kc*32 + quad*8 + j;
        rmast[rt][kc][j] = (double)x[((size_t)b*D_ + d)*T_ + t];
      }
  }

  half8 ah[2][4];
  auto makeAB = [&](){
#pragma unroll
    for (int rt=0;rt<2;++rt)
#pragma unroll
      for (int kc=0;kc<4;++kc){
        half8 h;
#pragma unroll
        for (int j=0;j<8;++j) h[j] = (_Float16)(float)rmast[rt][kc][j];
        ah[rt][kc] = h;
      }
  };
  makeAB();

  // 4 waves stage one 32KB chunk (8KB slab each, 8 DMA/lane of 16B)
  auto stage = [&](int c){
    const char* gsrc = (const char*)g_half + ((size_t)c<<15) + (wv<<13) + (ln<<4);
    char* ldst = (char*)sBh + ((c&1)<<15) + (wv<<13) + (ln<<4);
#pragma unroll
    for (int it=0; it<8; ++it)
      gld16(gsrc + it*1024, ldst + it*1024);
  };

  for (int i=tid; i<1024; i+=256) sCcQ[i] = sumsq[i];
  stage(0);
  __syncthreads();

  double lossd = 0.0;

  for (int q=0;q<Q_;++q){
    const float* cbq = cb + (size_t)q*C_*D_;

    float m1[2][4], m2[2][4]; int i1[2][4], i2[2][4];
#pragma unroll
    for (int rt=0;rt<2;++rt)
#pragma unroll
      for (int rg=0;rg<4;++rg){
        m1[rt][rg]=3.0e38f; i1[rt][rg]=0;
        m2[rt][rg]=3.0e38f; i2[rt][rg]=0;
      }

    for (int ch=0; ch<8; ++ch){
      const int gstep = q*8 + ch;
      const int nxt   = (gstep+1 < Q_*8) ? gstep+1 : 0;
      stage(nxt);                                       // 8 DMA into slot (gstep+1)&1
      asm volatile("s_waitcnt vmcnt(8)" ::: "memory");  // this chunk's DMA landed
      asm volatile("s_barrier" ::: "memory");           // all waves see chunk gstep
      const int slot = (gstep&1)<<14;                   // half-elem offset

#pragma unroll
      for (int itc=0; itc<4; ++itc){                    // 4 x 32-code groups
        float4_ acc[2][2];
#pragma unroll
        for (int a=0;a<2;++a)
#pragma unroll
          for (int c2=0;c2<2;++c2) acc[a][c2] = (float4_){0.f,0.f,0.f,0.f};
#pragma unroll
        for (int kc=0;kc<4;++kc){
          const int kgs = ((kc<<2) + quad) ^ col;
          half8 bf[2];
#pragma unroll
          for (int ct=0;ct<2;++ct){
            const int n = itc*32 + ct*16 + col;
            bf[ct] = *(const half8*)&sBh[slot + (n<<7) + (kgs<<3)];
          }
#pragma unroll
          for (int rt=0;rt<2;++rt)
#pragma unroll
            for (int ct=0;ct<2;++ct)
              acc[rt][ct] = __builtin_amdgcn_mfma_f32_16x16x32_f16(ah[rt][kc], bf[ct], acc[rt][ct], 0,0,0);
        }
#pragma unroll
        for (int ct=0;ct<2;++ct){
          const float cc = sCcQ[(ch<<7) + itc*32 + ct*16 + col];
          const int cid  = ch*8 + itc*2 + ct;           // global code = cid*16+col
#pragma unroll
          for (int rt=0;rt<2;++rt)
#pragma unroll
            for (int rg=0;rg<4;++rg){
              float s = fmaf(-2.0f, acc[rt][ct][rg], cc);
              if (s < m1[rt][rg]) {
                m2[rt][rg]=m1[rt][rg]; i2[rt][rg]=i1[rt][rg];
                m1[rt][rg]=s;          i1[rt][rg]=cid;
              } else if (s < m2[rt][rg]) {
                m2[rt][rg]=s;          i2[rt][rg]=cid;
              }
            }
        }
      }
      if (ch != 7)
        asm volatile("s_barrier" ::: "memory");  // reads done before next overwrite
    }

    // ---- publish per-lane top-2 to LDS (wave-private slab) ----
#pragma unroll
    for (int rt=0;rt<2;++rt)
#pragma unroll
      for (int rg=0;rg<4;++rg){
        const int row = rt*16 + quad*4 + rg;
        sCS[wv][row][col][0] = m1[rt][rg];  sCI[wv][row][col][0] = (i1[rt][rg]<<4)+col;
        sCS[wv][row][col][1] = m2[rt][rg];  sCI[wv][row][col][1] = (i2[rt][rg]<<4)+col;
      }

    // ---- lanes 0..31: scan 32 entries for own row -> sorted top-4 ----
    if (ln < 32){
      const int row = ln;
      float b0=3.0e38f,b1=3.0e38f,b2=3.0e38f,b3=3.0e38f;
      int   e0=0x7fffffff,e1=0x7fffffff,e2=0x7fffffff,e3=0x7fffffff;
#pragma unroll
      for (int c2=0;c2<32;++c2){
        const float s = sCS[wv][row][c2>>1][c2&1];
        const int  id = sCI[wv][row][c2>>1][c2&1];
        const bool l0 = (s<b0)||(s==b0&&id<e0);
        const bool l1 = (s<b1)||(s==b1&&id<e1);
        const bool l2 = (s<b2)||(s==b2&&id<e2);
        const bool l3 = (s<b3)||(s==b3&&id<e3);
        if (l3){
          b3 = l2 ? b2 : s;  e3 = l2 ? e2 : id;
          if (l2){
            b2 = l1 ? b1 : s;  e2 = l1 ? e1 : id;
            if (l1){
              b1 = l0 ? b0 : s;  e1 = l0 ? e0 : id;
              if (l0){ b0 = s; e0 = id; }
            }
          }
        }
      }
      sI4[wv][row][0]=e0; sI4[wv][row][1]=e1; sI4[wv][row][2]=e2; sI4[wv][row][3]=e3;
    }

    // ---- fp64 exact rescore of top-4 (streamed), winner update --------------
#pragma unroll
    for (int rt=0;rt<2;++rt){
      const int m = rt*16 + col;
      double bestS = 1.0e300; int bestJ = 0x7fffffff;
#pragma unroll
      for (int cnd=0;cnd<4;++cnd){
        const int jj = sI4[wv][m][cnd];
        const float* p = cbq + ((size_t)jj<<7) + (quad<<3);
        double s = 0.0;
#pragma unroll
        for (int kc=0;kc<4;++kc){
          float4_ a0 = *(const float4_*)(p + kc*32);
          float4_ a1 = *(const float4_*)(p + kc*32 + 4);
          float fv[8] = {a0.x,a0.y,a0.z,a0.w,a1.x,a1.y,a1.z,a1.w};
#pragma unroll
          for (int j=0;j<8;++j){
            double cd = (double)fv[j];
            s += cd*(cd - 2.0*rmast[rt][kc][j]);
          }
        }
        s += __shfl_xor(s, 16); s += __shfl_xor(s, 32);
        if ((s < bestS) || (s == bestS && jj < bestJ)){ bestS = s; bestJ = jj; }
      }
      const float* pw = cbq + ((size_t)bestJ<<7) + (quad<<3);
#pragma unroll
      for (int kc=0;kc<4;++kc){
        float4_ w0 = *(const float4_*)(pw + kc*32);
        float4_ w1 = *(const float4_*)(pw + kc*32 + 4);
        float fw[8] = {w0.x,w0.y,w0.z,w0.w,w1.x,w1.y,w1.z,w1.w};
#pragma unroll
        for (int j=0;j<8;++j){
          double rn = rmast[rt][kc][j] - (double)fw[j];
          rmast[rt][kc][j] = rn;
          lossd += rn*rn;
        }
      }
    }
    makeAB();
    if (q+1 < Q_){
      for (int i=tid; i<1024; i+=256) sCcQ[i] = sumsq[(q+1)*1024 + i];
    }
    __syncthreads();   // publishes sCcQ(q+1); guards dbuf/scratch reuse across q
  }

  // ---- epilogue: quantized = x - r_final ----
#pragma unroll
  for (int rt=0;rt<2;++rt){
    const int t = t0 + rt*16 + col;
#pragma unroll
    for (int kc=0;kc<4;++kc)
#pragma unroll
      for (int j=0;j<8;++j){
        const int d = kc*32 + quad*8 + j;
        const size_t o = ((size_t)b*D_ + d)*T_ + t;
        out[o] = (float)((double)x[o] - rmast[rt][kc][j]);
      }
  }
#pragma unroll
  for (int mk=1; mk<64; mk<<=1) lossd += __shfl_xor(lossd, mk);
  if (ln==0) atomicAdd(lossAcc, lossd);
}

__global__ void rvq_fin(const double* __restrict__ lossAcc, float* __restrict__ out){
  out[(size_t)B_*D_*T_] = (float)(*lossAcc * (1.0/((double)B_*(double)D_*(double)T_)));
}

extern "C" void kernel_launch(void* const* d_in, const int* in_sizes, int n_in,
                              void* d_out, int out_size, void* d_ws, size_t ws_size,
                              hipStream_t stream) {
  const float* x  = (const float*)d_in[0];   // [B, D, T] fp32
  const float* cb = (const float*)d_in[1];   // [Q, C, D] fp32
  float* out      = (float*)d_out;           // [B*D*T] quantized + [1] loss
  double* lossAcc = (double*)d_ws;
  float*  sumsq   = (float*)((char*)d_ws + 256);   // Q*C floats

  hipMemsetAsync(d_ws, 0, 256, stream);
  rvq_prep <<<Q_*C_/128, 256, 0, stream>>>(cb, sumsq);
  rvq_split<<<Q_*8,      256, 0, stream>>>(cb);
  rvq_main <<<(B_*T_)/128, 256, 0, stream>>>(x, cb, sumsq, lossAcc, out);
  rvq_fin  <<<1, 1, 0, stream>>>(lossAcc, out);
}